// Round 4
// baseline (860.667 us; speedup 1.0000x reference)
//
#include <hip/hip_runtime.h>
#include <stdint.h>

typedef uint32_t u32;
typedef unsigned long long u64;

#define NEGV (-1e9f)
#define MAXSEL 128
#define NCAND 16

__device__ __forceinline__ u32 f2ord(float f) {
  u32 x = __float_as_uint(f);
  return (x & 0x80000000u) ? ~x : (x | 0x80000000u);
}
__device__ __forceinline__ float ord2f(u32 u) {
  u32 x = (u & 0x80000000u) ? (u ^ 0x80000000u) : ~u;
  return __uint_as_float(x);
}

// ---- mask packer: int32 mask [2][2048][4096] -> u64 bits [2][2048][64] ----
__global__ __launch_bounds__(256)
void pack_mask(const int* __restrict__ mask, u64* __restrict__ mbits) {
  int w = blockIdx.x * 256 + threadIdx.x;  // word id, 262144 total
  const int4* p = (const int4*)(mask + (size_t)w * 64);
  u64 bits = 0;
#pragma unroll
  for (int j = 0; j < 16; ++j) {
    int4 m = p[j];
    if (m.x) bits |= 1ull << (j * 4 + 0);
    if (m.y) bits |= 1ull << (j * 4 + 1);
    if (m.z) bits |= 1ull << (j * 4 + 2);
    if (m.w) bits |= 1ull << (j * 4 + 3);
  }
  mbits[w] = bits;
}

// ---- C[M x 512] = A[M x 512] @ W[512 x 512] + bias (row-major out) ----
__global__ __launch_bounds__(256)
void gemm_bias(const float* __restrict__ A, const float* __restrict__ W,
               const float* __restrict__ bias, float* __restrict__ C) {
  __shared__ float As[16][68];
  __shared__ float Bs[16][64];
  const int tid = threadIdx.x;
  const int tx = tid & 15, ty = tid >> 4;
  const int n0 = blockIdx.x << 6, m0 = blockIdx.y << 6;
  float c[4][4] = {};
  for (int k0 = 0; k0 < 512; k0 += 16) {
    {
      const int row = tid >> 2, kp = (tid & 3) << 2;
      float4 av = *(const float4*)&A[(size_t)(m0 + row) * 512 + k0 + kp];
      As[kp + 0][row] = av.x;
      As[kp + 1][row] = av.y;
      As[kp + 2][row] = av.z;
      As[kp + 3][row] = av.w;
      const int kk = tid >> 4, np = (tid & 15) << 2;
      *(float4*)&Bs[kk][np] = *(const float4*)&W[(size_t)(k0 + kk) * 512 + n0 + np];
    }
    __syncthreads();
#pragma unroll
    for (int kk = 0; kk < 16; ++kk) {
      float4 a = *(const float4*)&As[kk][ty << 2];
      float4 b = *(const float4*)&Bs[kk][tx << 2];
      c[0][0] += a.x * b.x; c[0][1] += a.x * b.y; c[0][2] += a.x * b.z; c[0][3] += a.x * b.w;
      c[1][0] += a.y * b.x; c[1][1] += a.y * b.y; c[1][2] += a.y * b.z; c[1][3] += a.y * b.w;
      c[2][0] += a.z * b.x; c[2][1] += a.z * b.y; c[2][2] += a.z * b.z; c[2][3] += a.z * b.w;
      c[3][0] += a.w * b.x; c[3][1] += a.w * b.y; c[3][2] += a.w * b.z; c[3][3] += a.w * b.w;
    }
    __syncthreads();
  }
  float4 bv = *(const float4*)&bias[n0 + (tx << 2)];
#pragma unroll
  for (int i = 0; i < 4; ++i) {
    float4 o;
    o.x = c[i][0] + bv.x; o.y = c[i][1] + bv.y;
    o.z = c[i][2] + bv.z; o.w = c[i][3] + bv.w;
    *(float4*)&C[(size_t)(m0 + (ty << 2) + i) * 512 + n0 + (tx << 2)] = o;
  }
}

// ---- same GEMM math, but stores k-major transposed ----
__global__ __launch_bounds__(256)
void gemm_bias_T(const float* __restrict__ A, const float* __restrict__ W,
                 const float* __restrict__ bias, float* __restrict__ CT, int qsh) {
  __shared__ float As[16][68];
  __shared__ float Bs[16][64];
  const int tid = threadIdx.x;
  const int tx = tid & 15, ty = tid >> 4;
  const int n0 = blockIdx.x << 6, m0 = blockIdx.y << 6;
  float c[4][4] = {};
  for (int k0 = 0; k0 < 512; k0 += 16) {
    {
      const int row = tid >> 2, kp = (tid & 3) << 2;
      float4 av = *(const float4*)&A[(size_t)(m0 + row) * 512 + k0 + kp];
      As[kp + 0][row] = av.x;
      As[kp + 1][row] = av.y;
      As[kp + 2][row] = av.z;
      As[kp + 3][row] = av.w;
      const int kk = tid >> 4, np = (tid & 15) << 2;
      *(float4*)&Bs[kk][np] = *(const float4*)&W[(size_t)(k0 + kk) * 512 + n0 + np];
    }
    __syncthreads();
#pragma unroll
    for (int kk = 0; kk < 16; ++kk) {
      float4 a = *(const float4*)&As[kk][ty << 2];
      float4 b = *(const float4*)&Bs[kk][tx << 2];
      c[0][0] += a.x * b.x; c[0][1] += a.x * b.y; c[0][2] += a.x * b.z; c[0][3] += a.x * b.w;
      c[1][0] += a.y * b.x; c[1][1] += a.y * b.y; c[1][2] += a.y * b.z; c[1][3] += a.y * b.w;
      c[2][0] += a.z * b.x; c[2][1] += a.z * b.y; c[2][2] += a.z * b.z; c[2][3] += a.z * b.w;
      c[3][0] += a.w * b.x; c[3][1] += a.w * b.y; c[3][2] += a.w * b.z; c[3][3] += a.w * b.w;
    }
    __syncthreads();
  }
  float4 bv = *(const float4*)&bias[n0 + (tx << 2)];
  float bvv[4] = {bv.x, bv.y, bv.z, bv.w};
  const int qlen = 1 << qsh;
  const int qmask = qlen - 1;
#pragma unroll
  for (int i = 0; i < 4; ++i) {
#pragma unroll
    for (int j = 0; j < 4; ++j) {
      float val = c[i][j] + bvv[j];
      int m = m0 + (ty << 2) + i;
      int n = n0 + (tx << 2) + j;
      int h = n >> 6, d = n & 63;
      int bb = m >> qsh, q = m & qmask;
      CT[(((size_t)bb * 8 + h) * 64 + d) * qlen + q] = val;
    }
  }
}

// ---- scores: 128(q) x 128(s) tile per block, 8x8 micro, k-major LDS ----
__global__ __launch_bounds__(256)
void score_kernel(const float* __restrict__ qT, const float* __restrict__ kT,
                  const u64* __restrict__ mbits, float* __restrict__ sbuf, int sl0) {
  __shared__ float Qs[64][128];
  __shared__ float Ks[64][128];
  const int sl = sl0 + blockIdx.z;
  const int b = sl >> 3, h = sl & 7;
  const int s0 = blockIdx.x << 7, q0 = blockIdx.y << 7;
  const int tid = threadIdx.x;
  const float* qbase = qT + (size_t)sl * 64 * 2048 + q0;
  const float* kbase = kT + (size_t)h * 64 * 4096 + s0;
  float4* Qf = (float4*)&Qs[0][0];
  float4* Kf = (float4*)&Ks[0][0];
#pragma unroll
  for (int u = 0; u < 8; ++u) {
    int i = (u << 8) + tid;
    int row = i >> 5, col = (i & 31) << 2;
    Qf[i] = *(const float4*)(qbase + (size_t)row * 2048 + col);
    Kf[i] = *(const float4*)(kbase + (size_t)row * 4096 + col);
  }
  __syncthreads();
  const int tx = tid & 15, ty = tid >> 4;
  float c[8][8] = {};
#pragma unroll 4
  for (int g = 0; g < 16; ++g) {
    const int kk = g << 2;
    float qa[8][4], kb[8][4];
#pragma unroll
    for (int t = 0; t < 4; ++t) {
#pragma unroll
      for (int i = 0; i < 8; ++i) qa[i][t] = Qs[kk + t][(ty << 3) + i];
#pragma unroll
      for (int j = 0; j < 4; ++j) {
        kb[j][t]     = Ks[kk + t][(tx << 2) + j];
        kb[4 + j][t] = Ks[kk + t][64 + (tx << 2) + j];
      }
    }
#pragma unroll
    for (int i = 0; i < 8; ++i)
#pragma unroll
      for (int j = 0; j < 8; ++j)
        c[i][j] += qa[i][0] * kb[j][0] + qa[i][1] * kb[j][1]
                 + qa[i][2] * kb[j][2] + qa[i][3] * kb[j][3];
  }
  float* srow = sbuf + ((size_t)blockIdx.z * 2048 + q0) * 4096 + s0;
  const u64* mrow = mbits + ((size_t)(b * 2048 + q0)) * 64 + (s0 >> 6);
#pragma unroll
  for (int i = 0; i < 8; ++i) {
    const int row = (ty << 3) + i;
    u64 wA = mrow[(size_t)row * 64];
    u64 wB = mrow[(size_t)row * 64 + 1];
    float4 o0, o1;
    o0.x = ((wA >> ((tx << 2) + 0)) & 1) ? c[i][0] * 0.125f : NEGV;
    o0.y = ((wA >> ((tx << 2) + 1)) & 1) ? c[i][1] * 0.125f : NEGV;
    o0.z = ((wA >> ((tx << 2) + 2)) & 1) ? c[i][2] * 0.125f : NEGV;
    o0.w = ((wA >> ((tx << 2) + 3)) & 1) ? c[i][3] * 0.125f : NEGV;
    o1.x = ((wB >> ((tx << 2) + 0)) & 1) ? c[i][4] * 0.125f : NEGV;
    o1.y = ((wB >> ((tx << 2) + 1)) & 1) ? c[i][5] * 0.125f : NEGV;
    o1.z = ((wB >> ((tx << 2) + 2)) & 1) ? c[i][6] * 0.125f : NEGV;
    o1.w = ((wB >> ((tx << 2) + 3)) & 1) ? c[i][7] * 0.125f : NEGV;
    *(float4*)&srow[(size_t)row * 4096 + (tx << 2)] = o0;
    *(float4*)&srow[(size_t)row * 4096 + 64 + (tx << 2)] = o1;
  }
}

// ---- select v5: one WAVE per q-row (block=64), register-resident, pipelined gather ----
__global__ __launch_bounds__(64, 2)
void select_kernel(const float* __restrict__ sbuf, const float* __restrict__ vbuf,
                   float* __restrict__ ctxbuf, int sl0) {
  const int sl = sl0 + blockIdx.y;
  const int b = sl >> 3, h = sl & 7;
  const int qi = blockIdx.x;
  const int lane = threadIdx.x;  // 0..63
  __shared__ u32 cv_lds[NCAND][64];
  __shared__ u64 list[MAXSEL];

  const float* srow = sbuf + ((size_t)blockIdx.y * 2048 + qi) * 4096;
  const u32 ordneg = f2ord(NEGV);
  const u64 lmask_lt = (1ull << lane) - 1ull;

  u32 u[64];
#pragma unroll
  for (int j = 0; j < 16; ++j) {
    float4 v = *(const float4*)(srow + (j << 8) + (lane << 2));
    u[j * 4 + 0] = f2ord(v.x);
    u[j * 4 + 1] = f2ord(v.y);
    u[j * 4 + 2] = f2ord(v.z);
    u[j * 4 + 3] = f2ord(v.w);
  }
  // lane max -> wave max (fm) and wave min-of-lane-maxes (lo0, a valid lower
  // bound on the 64th-largest: 64 lanes each contribute >=1 element >= lo0)
  u32 lmax = 0;
#pragma unroll
  for (int e = 0; e < 64; ++e) lmax = u[e] > lmax ? u[e] : lmax;
  u32 mx = lmax, mn = lmax;
#pragma unroll
  for (int off = 32; off; off >>= 1) {
    u32 a = (u32)__shfl_xor((int)mx, off, 64);
    u32 c = (u32)__shfl_xor((int)mn, off, 64);
    mx = a > mx ? a : mx;
    mn = c < mn ? c : mn;
  }
  const float fm = ord2f(mx);
  const u32 lo0 = mn;

  // compact candidate VALUES (>= lo0) into LDS [slot][lane]
  int cnt = 0;
#pragma unroll
  for (int e = 0; e < 64; ++e) {
    u32 ue = u[e];
    if (ue >= lo0 && ue != ordneg) {
      if (cnt < NCAND) cv_lds[cnt][lane] = ue;
      cnt++;
    }
  }
  const bool fb = (__ballot(cnt > NCAND) != 0ull);

  u32 lo = lo0, hi = mx + 1;
  if (!fb) {
#pragma unroll
    for (int j = 0; j < NCAND; ++j)
      if (j >= cnt) cv_lds[j][lane] = 0;  // zero-fill: never counted (mid > lo0 > 0)
    u32 cv[NCAND];
#pragma unroll
    for (int j = 0; j < NCAND; ++j) cv[j] = cv_lds[j][lane];
    while (hi - lo > 1) {
      u32 mid = lo + ((hi - lo) >> 1);
      int c2 = 0;
#pragma unroll
      for (int j = 0; j < NCAND; ++j)
        c2 += __popcll(__ballot(cv[j] >= mid));
      if (c2 >= 64) lo = mid; else hi = mid;
    }
  } else {
    // rare fallback: search over all 64 register elements
    while (hi - lo > 1) {
      u32 mid = lo + ((hi - lo) >> 1);
      int c2 = 0;
#pragma unroll
      for (int e = 0; e < 64; ++e)
        c2 += __popcll(__ballot(u[e] >= mid));
      if (c2 >= 64) lo = mid; else hi = mid;
    }
  }
  const u32 thr = lo;

  // extraction: survivors -> packed (sidx, ev) list via ballot-prefix; esum
  float esum = 0.f;
  int base = 0;
#pragma unroll
  for (int e = 0; e < 64; ++e) {
    u32 ue = u[e];
    bool pred = (ue >= thr) && (ue != ordneg);
    float ev = __expf(ord2f(ue) - fm);
    u64 m = __ballot(pred);
    int ofs = base + __popcll(m & lmask_lt);
    if (pred && ofs < MAXSEL) {
      int sidx = ((e >> 2) << 8) + (lane << 2) + (e & 3);
      list[ofs] = ((u64)(u32)sidx << 32) | (u64)__float_as_uint(ev);
      esum += ev;
    }
    base += (int)__popcll(m);
  }
  int nsel = base < MAXSEL ? base : MAXSEL;
  int pad = (4 - (nsel & 3)) & 3;
  if (lane < pad && nsel + lane < MAXSEL) list[nsel + lane] = 0;  // ev=0, idx=0
  int n4 = nsel + pad;
  if (n4 > MAXSEL) n4 = MAXSEL;

#pragma unroll
  for (int off = 32; off; off >>= 1) esum += __shfl_xor(esum, off, 64);
  const float rs = 1.0f / esum;

  // gather: groups of 4 independent (LDS read -> V row load -> fmac), 4 accumulators
  const float* vb = vbuf + h * 64 + lane;
  float a0 = 0.f, a1 = 0.f, a2 = 0.f, a3 = 0.f;
  for (int g = 0; g < n4; g += 4) {
    u64 p0 = list[g + 0], p1 = list[g + 1], p2 = list[g + 2], p3 = list[g + 3];
    a0 += __uint_as_float((u32)p0) * vb[(size_t)(p0 >> 32) * 512];
    a1 += __uint_as_float((u32)p1) * vb[(size_t)(p1 >> 32) * 512];
    a2 += __uint_as_float((u32)p2) * vb[(size_t)(p2 >> 32) * 512];
    a3 += __uint_as_float((u32)p3) * vb[(size_t)(p3 >> 32) * 512];
  }
  float acc = (a0 + a1) + (a2 + a3);
  ctxbuf[((size_t)(b * 2048 + qi)) * 512 + h * 64 + lane] = acc * rs;
}

extern "C" void kernel_launch(void* const* d_in, const int* in_sizes, int n_in,
                              void* d_out, int out_size, void* d_ws, size_t ws_size,
                              hipStream_t stream) {
  const float* main_in = (const float*)d_in[0];
  const float* side_in = (const float*)d_in[1];
  const int*   mask    = (const int*)d_in[2];
  const float* Wq = (const float*)d_in[3];
  const float* bq = (const float*)d_in[4];
  const float* Wk = (const float*)d_in[5];
  const float* bk = (const float*)d_in[6];
  const float* Wv = (const float*)d_in[7];
  const float* bv = (const float*)d_in[8];
  const float* Wo = (const float*)d_in[9];
  const float* bo = (const float*)d_in[10];
  float* out = (float*)d_out;

  char* ws = (char*)d_ws;
  float* qT   = (float*)(ws);                       // 8 MB  [16][64][2048]
  float* kT   = (float*)(ws + ((size_t)8 << 20));   // 8 MB  [8][64][4096]
  float* vbuf = (float*)(ws + ((size_t)16 << 20));  // 8 MB  [4096][512]
  float* ctxb = (float*)(ws + ((size_t)24 << 20));  // 8 MB  [4096][512]
  u64* mbits  = (u64*)(ws + ((size_t)32 << 20));    // 2 MB  [2][2048][64]
  float* sbuf = (float*)(ws + ((size_t)34 << 20));  // nz * 32 MB
  const size_t base = (size_t)34 << 20;
  const size_t sliceb = (size_t)2048 * 4096 * 4;

  int nz = 1;
  if (ws_size > base + sliceb) {
    size_t m = (ws_size - base) / sliceb;
    nz = (int)(m > 16 ? 16 : m);
  }

  pack_mask<<<1024, 256, 0, stream>>>(mask, mbits);
  gemm_bias_T<<<dim3(8, 64), 256, 0, stream>>>(main_in, Wq, bq, qT, 11);
  gemm_bias_T<<<dim3(8, 64), 256, 0, stream>>>(side_in, Wk, bk, kT, 12);
  gemm_bias  <<<dim3(8, 64), 256, 0, stream>>>(side_in, Wv, bv, vbuf);

  for (int sl0 = 0; sl0 < 16; sl0 += nz) {
    int z = nz < (16 - sl0) ? nz : (16 - sl0);
    score_kernel <<<dim3(32, 16, z), 256, 0, stream>>>(qT, kT, mbits, sbuf, sl0);
    select_kernel<<<dim3(2048, z), 64, 0, stream>>>(sbuf, vbuf, ctxb, sl0);
  }

  gemm_bias<<<dim3(8, 64), 256, 0, stream>>>(ctxb, Wo, bo, out);
}